// Round 20
// baseline (340.890 us; speedup 1.0000x reference)
//
#include <hip/hip_runtime.h>
#include <hip/hip_bf16.h>
#include <math.h>

typedef __bf16 bf16x8 __attribute__((ext_vector_type(8)));
typedef float  f32x4  __attribute__((ext_vector_type(4)));
typedef __hip_bfloat16 bf16;

#define DIM  1024
#define MLPD 4096
#define NB   4
#define SEQ  2048
#define ROWS (NB * SEQ) /* 8192 */

__device__ __forceinline__ void gload_lds16(const void* g, void* l) {
  __builtin_amdgcn_global_load_lds(
      (__attribute__((address_space(1))) void*)(g),
      (__attribute__((address_space(3))) void*)(l), 16, 0, 0);
}

__device__ __forceinline__ void bar() {
  asm volatile("" ::: "memory");
  __builtin_amdgcn_s_barrier();
  asm volatile("" ::: "memory");
}

template <int N>
__device__ __forceinline__ void vmw() {
  asm volatile("s_waitcnt vmcnt(%0)" ::"n"(N) : "memory");
}

// exact-GELU via A&S 7.1.26 erf approx (max err ~1.5e-7 << 0.09 headroom).
__device__ __forceinline__ float gelu_exact_fast(float v) {
  const float x  = v * 0.70710678118654752f;
  const float ax = fabsf(x);
  const float t  = __builtin_amdgcn_rcpf(1.0f + 0.3275911f * ax);
  const float p  = t * (0.254829592f +
                   t * (-0.284496736f +
                   t * (1.421413741f +
                   t * (-1.453152027f + t * 1.061405429f))));
  float erf = 1.0f - p * __expf(-x * x);
  erf = copysignf(erf, x);
  return 0.5f * v * (1.0f + erf);
}

// ---------------------------------------------------------------------------
// 256x256 8-phase GEMM (r13-r19, verified): QK-proj + scores.
// EPI: 0=+bias->bf16 | 5=*scale->bf16
// ---------------------------------------------------------------------------
template <int EPI>
__global__ __launch_bounds__(512, 2) void gemm256(
    const bf16* __restrict__ A,  long aBatch, int lda,
    const bf16* __restrict__ Bt, long bBatch, int ldb,
    void* __restrict__ Cout,     long cBatch, int ldc,
    const float* __restrict__ bias, int K, float scale)
{
  extern __shared__ char smem[];

  const int gx = gridDim.x, gy = gridDim.y;
  int flat = blockIdx.x + gx * (blockIdx.y + gy * blockIdx.z);
  const int nwg = gx * gy * gridDim.z;
  flat = (flat & 7) * (nwg >> 3) + (flat >> 3);
  const int bx = flat % gx;
  const int t2 = flat / gx;
  const int by = t2 % gy;
  const int bz = t2 / gy;

  const long rowBase = (long)by * 256;
  const long colBase = (long)bx * 256;
  const long ldaB = (long)lda * 2, ldbB = (long)ldb * 2;
  const char* Ag = (const char*)(A + bz * aBatch + rowBase * lda);
  const char* Bg = (const char*)(Bt + bz * bBatch + colBase * ldb);

  const int tid  = threadIdx.x;
  const int lane = tid & 63;
  const int wave = tid >> 6;
  const int wm = wave >> 2, wn = wave & 3;
  const int fr = lane & 15, fq = lane >> 4;
  const int fh2 = fr >> 1;
  const int sA = (((fr & 1) << 2) | fq) ^ fh2;
  const int rdCom = fh2 * 128 + sA * 16;

  long offA[2], offB[2];
#pragma unroll
  for (int li = 0; li < 2; ++li) {
    const int d = li * 512 + tid;
    {
      const int wms = d >> 9, kks = (d >> 8) & 1, w = d & 255;
      const int pr = w >> 3, s = w & 7, u = s ^ (pr & 7);
      offA[li] = (long)(wms * 128 + pr * 2 + (u >> 2)) * ldaB +
                 kks * 64 + (u & 3) * 16;
    }
    {
      const int wns = d >> 8, kkb = (d >> 7) & 1, w = d & 127;
      const int pr = w >> 3, s = w & 7, u = s ^ (pr & 7);
      offB[li] = (long)(wns * 64 + pr * 2 + (u >> 2)) * ldbB +
                 kkb * 64 + (u & 3) * 16;
    }
  }
  const int dstOff = tid * 16;
  const long aHalf = ldaB << 6;
  const long bHalf = ldbB << 5;

  const int NT = K >> 6;

  bf16x8 a[4][2], b[2][2][2];
  f32x4 acc[8][4] = {};

#define STG_A(J, mh)                                                           \
  do {                                                                         \
    char* _d = smem + (((J) & 1) << 16) + (mh) * 16384 + dstOff;               \
    const char* _s = Ag + (J) * 128 + (mh) * aHalf;                            \
    gload_lds16(_s + offA[0], _d);                                             \
    gload_lds16(_s + offA[1], _d + 8192);                                      \
  } while (0)

#define STG_B(J, nh)                                                           \
  do {                                                                         \
    char* _d = smem + (((J) & 1) << 16) + 32768 + (nh) * 16384 + dstOff;       \
    const char* _s = Bg + (J) * 128 + (nh) * bHalf;                            \
    gload_lds16(_s + offB[0], _d);                                             \
    gload_lds16(_s + offB[1], _d + 8192);                                      \
  } while (0)

#define LDA(mh, J)                                                             \
  do {                                                                         \
    const char* _b = smem + (((J) & 1) << 16) + (mh) * 16384 + wm * 8192 +     \
                     rdCom;                                                    \
    _Pragma("unroll") for (int m = 0; m < 4; ++m)                              \
      _Pragma("unroll") for (int kk = 0; kk < 2; ++kk)                         \
        a[m][kk] = *(const bf16x8*)(_b + kk * 4096 + m * 1024);                \
  } while (0)

#define LDB(nh, J)                                                             \
  do {                                                                         \
    const char* _b = smem + (((J) & 1) << 16) + 32768 + (nh) * 16384 +         \
                     wn * 4096 + rdCom;                                        \
    _Pragma("unroll") for (int n = 0; n < 2; ++n)                              \
      _Pragma("unroll") for (int kk = 0; kk < 2; ++kk)                         \
        b[nh][n][kk] = *(const bf16x8*)(_b + kk * 2048 + n * 1024);            \
  } while (0)

#define MM(mh, nh)                                                             \
  do {                                                                         \
    __builtin_amdgcn_s_setprio(1);                                             \
    _Pragma("unroll") for (int m = 0; m < 4; ++m)                              \
      _Pragma("unroll") for (int n = 0; n < 2; ++n)                            \
        _Pragma("unroll") for (int kk = 0; kk < 2; ++kk)                       \
          acc[(mh) * 4 + m][(nh) * 2 + n] =                                    \
              __builtin_amdgcn_mfma_f32_16x16x32_bf16(                         \
                  a[m][kk], b[nh][n][kk], acc[(mh) * 4 + m][(nh) * 2 + n],     \
                  0, 0, 0);                                                    \
    __builtin_amdgcn_s_setprio(0);                                             \
  } while (0)

#define LGKM0 asm volatile("s_waitcnt lgkmcnt(0)" ::: "memory")

#define TILE(J, S1, S2, VN)                                                    \
  do {                                                                         \
    LDA(0, J); LDB(0, J);                                                      \
    if (S1) STG_A((J) + 1, 1);                                                 \
    bar(); LGKM0; MM(0, 0); bar();                                             \
    LDB(1, J);                                                                 \
    if (S2) STG_A((J) + 2, 0);                                                 \
    bar(); LGKM0; MM(0, 1); bar();                                             \
    LDA(1, J);                                                                 \
    if (S2) STG_B((J) + 2, 0);                                                 \
    bar(); LGKM0; MM(1, 1); bar();                                             \
    if (S2) STG_B((J) + 2, 1);                                                 \
    vmw<VN>(); bar(); MM(1, 0); bar();                                         \
  } while (0)

  STG_A(0, 0); STG_B(0, 0); STG_B(0, 1); STG_A(0, 1);
  STG_A(1, 0); STG_B(1, 0); STG_B(1, 1);
  vmw<6>(); bar();

  for (int j = 0; j < NT - 2; ++j) TILE(j, true, true, 6);
  TILE(NT - 2, true, false, 0);
  TILE(NT - 1, false, false, 63);

#undef STG_A
#undef STG_B
#undef LDA
#undef LDB
#undef MM
#undef TILE

#pragma unroll
  for (int mh = 0; mh < 2; ++mh)
#pragma unroll
    for (int m = 0; m < 4; ++m)
#pragma unroll
      for (int nh = 0; nh < 2; ++nh)
#pragma unroll
        for (int n = 0; n < 2; ++n) {
          const long col = colBase + wn * 64 + nh * 32 + n * 16 + fr;
#pragma unroll
          for (int e = 0; e < 4; ++e) {
            const long r = rowBase + wm * 128 + mh * 64 + m * 16 + fq * 4 + e;
            float v = acc[mh * 4 + m][nh * 2 + n][e];
            if constexpr (EPI == 0) {
              v += bias[col];
              ((bf16*)Cout)[bz * cBatch + r * ldc + col] = __float2bfloat16(v);
            } else {  // 5
              ((bf16*)Cout)[bz * cBatch + r * ldc + col] =
                  __float2bfloat16(v * scale);
            }
          }
        }
}

// ---------------------------------------------------------------------------
// r10 128x128 GEMM (vT / PV / MLP1 — shapes where 4 blocks/CU wins, r17/r19
// measured): BK=32, 4 waves, 32 KiB dbuf, period-2 drains, conflict-free
// row-pair LDS. EPI: 2=+resid->fp32 | 3=+bias,gelu->bf16 | 6=+bias[ROW]->bf16
// ---------------------------------------------------------------------------
template <int EPI>
__global__ __launch_bounds__(256, 4) void gemm128(
    const bf16* __restrict__ A,  long aBatch, int lda,
    const bf16* __restrict__ Bt, long bBatch, int ldb,
    void* __restrict__ Cout,     long cBatch, int ldc,
    const float* __restrict__ bias,
    const float* __restrict__ resid, long rBatch, int ldr,
    int K, float scale)
{
  __shared__ char smem[2][16384];

  const int gx = gridDim.x, gy = gridDim.y;
  const int n = gx * gy * gridDim.z;
  const int f = blockIdx.x + gx * (blockIdx.y + gy * blockIdx.z);
  const int o = (f & 7) * (n >> 3) + (f >> 3);
  const int sx = gx >> 3;
  int st = o >> 6;
  const int w = o & 63;
  const int spz = sx * (gy >> 3);
  const int bz = st / spz; st -= bz * spz;
  const int sty = st / sx, stx = st - sty * sx;
  const int by = sty * 8 + (w >> 3), bx = stx * 8 + (w & 7);

  const long rowBase = (long)by * 128;
  const long colBase = (long)bx * 128;
  const long ldaB = (long)lda * 2, ldbB = (long)ldb * 2;
  const char* Ag = (const char*)(A + bz * aBatch + rowBase * lda);
  const char* Bg = (const char*)(Bt + bz * bBatch + colBase * ldb);

  const int tid  = threadIdx.x;
  const int lane = tid & 63;
  const int wave = tid >> 6;
  const int wm = wave >> 1, wn = wave & 1;
  const int fr = lane & 15, fq = lane >> 4;

  const int fh = fr >> 1;
  const int sA = (((fr & 1) << 2) | fq) ^ fh;
  const int laneRd = fh * 128 + sA * 16;
  const int abase = wm * 4096 + laneRd;
  const int bbase = 8192 + wn * 4096 + laneRd;

  const int t0   = wave * 128 + lane;
  const int r2   = t0 >> 3;
  const int u0   = (t0 & 7) ^ (r2 & 7);
  const int row0 = r2 * 2 + (u0 >> 2);
  const int kc0  = u0 & 3;
  const char* aSrc0 = Ag + (long)row0 * ldaB + kc0 * 16;
  const char* aSrc1 = aSrc0 + 16 * ldaB;
  const char* bSrc0 = Bg + (long)row0 * ldbB + kc0 * 16;
  const char* bSrc1 = bSrc0 + 16 * ldbB;
  const int doff = wave * 2048 + lane * 16;

  const int NT = K >> 5;
  f32x4 acc[4][4] = {};

#define STAGE(WB)                                                              \
  do {                                                                         \
    gload_lds16(aSrc0, &smem[WB][doff]);                                       \
    gload_lds16(aSrc1, &smem[WB][doff + 1024]);                                \
    gload_lds16(bSrc0, &smem[WB][8192 + doff]);                                \
    gload_lds16(bSrc1, &smem[WB][8192 + doff + 1024]);                         \
    aSrc0 += 64; aSrc1 += 64; bSrc0 += 64; bSrc1 += 64;                        \
  } while (0)

#define READMM(RB)                                                             \
  do {                                                                         \
    const char* _r = &smem[RB][0];                                             \
    bf16x8 av[4], bv_[4];                                                      \
    _Pragma("unroll") for (int m = 0; m < 4; ++m)                              \
      av[m] = *(const bf16x8*)(_r + abase + m * 1024);                         \
    _Pragma("unroll") for (int nn = 0; nn < 4; ++nn)                           \
      bv_[nn] = *(const bf16x8*)(_r + bbase + nn * 1024);                      \
    __builtin_amdgcn_s_setprio(1);                                             \
    _Pragma("unroll") for (int m = 0; m < 4; ++m)                              \
      _Pragma("unroll") for (int nn = 0; nn < 4; ++nn)                         \
        acc[m][nn] = __builtin_amdgcn_mfma_f32_16x16x32_bf16(                  \
            av[m], bv_[nn], acc[m][nn], 0, 0, 0);                              \
    __builtin_amdgcn_s_setprio(0);                                             \
  } while (0)

  for (int t = 0; t < NT; t += 2) {
    STAGE(0);
    STAGE(1);
    vmw<0>(); bar();
    READMM(0);
    READMM(1);
    bar();
  }

#undef STAGE
#undef READMM

#pragma unroll
  for (int m = 0; m < 4; ++m) {
#pragma unroll
    for (int nn = 0; nn < 4; ++nn) {
      const long col = colBase + wn * 64 + nn * 16 + fr;
#pragma unroll
      for (int e = 0; e < 4; ++e) {
        const long r = rowBase + wm * 64 + m * 16 + fq * 4 + e;
        float v = acc[m][nn][e];
        if constexpr (EPI == 2) {
          v += resid[bz * rBatch + r * ldr + col];
          ((float*)Cout)[bz * cBatch + r * ldc + col] = v;
        } else if constexpr (EPI == 3) {
          v += bias[col];
          ((bf16*)Cout)[bz * cBatch + r * ldc + col] =
              __float2bfloat16(gelu_exact_fast(v));
        } else {  // 6: +bias indexed by ROW, bf16 out
          v += bias[r];
          ((bf16*)Cout)[bz * cBatch + r * ldc + col] = __float2bfloat16(v);
        }
      }
    }
  }
}

// ---------------------------------------------------------------------------
// r18 DEEP 128x128 GEMM (MLP2 only — K=4096, 512 wg: 2 blocks/CU is
// grid-forced, period-old vmcnt(8) drain-age is pure gain; r18 A/B −11 us).
// 4 sub-buffers (2 pairs, 64 KiB); requires K%128==0.
// EPI: 4=+bias+resid->fp32
// ---------------------------------------------------------------------------
template <int EPI>
__global__ __launch_bounds__(256, 2) void gemm128d(
    const bf16* __restrict__ A,  long aBatch, int lda,
    const bf16* __restrict__ Bt, long bBatch, int ldb,
    void* __restrict__ Cout,     long cBatch, int ldc,
    const float* __restrict__ bias,
    const float* __restrict__ resid, long rBatch, int ldr,
    int K, float scale)
{
  __shared__ char smem[4][16384];

  const int gx = gridDim.x, gy = gridDim.y;
  const int n = gx * gy * gridDim.z;
  const int f = blockIdx.x + gx * (blockIdx.y + gy * blockIdx.z);
  const int o = (f & 7) * (n >> 3) + (f >> 3);
  const int sx = gx >> 3;
  int st = o >> 6;
  const int w = o & 63;
  const int spz = sx * (gy >> 3);
  const int bz = st / spz; st -= bz * spz;
  const int sty = st / sx, stx = st - sty * sx;
  const int by = sty * 8 + (w >> 3), bx = stx * 8 + (w & 7);

  const long rowBase = (long)by * 128;
  const long colBase = (long)bx * 128;
  const long ldaB = (long)lda * 2, ldbB = (long)ldb * 2;
  const char* Ag = (const char*)(A + bz * aBatch + rowBase * lda);
  const char* Bg = (const char*)(Bt + bz * bBatch + colBase * ldb);

  const int tid  = threadIdx.x;
  const int lane = tid & 63;
  const int wave = tid >> 6;
  const int wm = wave >> 1, wn = wave & 1;
  const int fr = lane & 15, fq = lane >> 4;

  const int fh = fr >> 1;
  const int sA = (((fr & 1) << 2) | fq) ^ fh;
  const int laneRd = fh * 128 + sA * 16;
  const int abase = wm * 4096 + laneRd;
  const int bbase = 8192 + wn * 4096 + laneRd;

  const int t0   = wave * 128 + lane;
  const int r2   = t0 >> 3;
  const int u0   = (t0 & 7) ^ (r2 & 7);
  const int row0 = r2 * 2 + (u0 >> 2);
  const int kc0  = u0 & 3;
  const char* aSrc0 = Ag + (long)row0 * ldaB + kc0 * 16;
  const char* aSrc1 = aSrc0 + 16 * ldaB;
  const char* bSrc0 = Bg + (long)row0 * ldbB + kc0 * 16;
  const char* bSrc1 = bSrc0 + 16 * ldbB;
  const int doff = wave * 2048 + lane * 16;

  const int NP = K >> 6;   // periods of 2 K-tiles; NP even required
  f32x4 acc[4][4] = {};

#define STAGE(WB)                                                              \
  do {                                                                         \
    gload_lds16(aSrc0, &smem[WB][doff]);                                       \
    gload_lds16(aSrc1, &smem[WB][doff + 1024]);                                \
    gload_lds16(bSrc0, &smem[WB][8192 + doff]);                                \
    gload_lds16(bSrc1, &smem[WB][8192 + doff + 1024]);                         \
    aSrc0 += 64; aSrc1 += 64; bSrc0 += 64; bSrc1 += 64;                        \
  } while (0)

#define READMM(RB)                                                             \
  do {                                                                         \
    const char* _r = &smem[RB][0];                                             \
    bf16x8 av[4], bv_[4];                                                      \
    _Pragma("unroll") for (int m = 0; m < 4; ++m)                              \
      av[m] = *(const bf16x8*)(_r + abase + m * 1024);                         \
    _Pragma("unroll") for (int nn = 0; nn < 4; ++nn)                           \
      bv_[nn] = *(const bf16x8*)(_r + bbase + nn * 1024);                      \
    __builtin_amdgcn_s_setprio(1);                                             \
    _Pragma("unroll") for (int m = 0; m < 4; ++m)                              \
      _Pragma("unroll") for (int nn = 0; nn < 4; ++nn)                         \
        acc[m][nn] = __builtin_amdgcn_mfma_f32_16x16x32_bf16(                  \
            av[m], bv_[nn], acc[m][nn], 0, 0, 0);                              \
    __builtin_amdgcn_s_setprio(0);                                             \
  } while (0)

  // prologue: period-0 pair (tiles 0,1) -> subs 0,1
  STAGE(0); STAGE(1);

  for (int it = 0; it < NP; it += 2) {
    STAGE(2); STAGE(3);
    vmw<8>(); bar();            // retires pair{0,1}'s loads (1 period old)
    READMM(0); READMM(1);
    bar();
    if (it + 2 < NP) { STAGE(0); STAGE(1); vmw<8>(); }
    else vmw<0>();
    bar();
    READMM(2); READMM(3);
    bar();
  }

#undef STAGE
#undef READMM

#pragma unroll
  for (int m = 0; m < 4; ++m) {
#pragma unroll
    for (int nn = 0; nn < 4; ++nn) {
      const long col = colBase + wn * 64 + nn * 16 + fr;
#pragma unroll
      for (int e = 0; e < 4; ++e) {
        const long r = rowBase + wm * 64 + m * 16 + fq * 4 + e;
        float v = acc[m][nn][e];
        if constexpr (EPI == 4) {
          v += bias[col] + resid[r * (long)ldr + col];
          ((float*)Cout)[bz * cBatch + r * ldc + col] = v;
        }
      }
    }
  }
}

// ---------------------------------------------------------------------------
__global__ __launch_bounds__(256) void ln_kernel(
    const float* __restrict__ x, const float* __restrict__ gamma,
    const float* __restrict__ beta, bf16* __restrict__ out)
{
  const long row = blockIdx.x;
  const float4 v = ((const float4*)(x + row * DIM))[threadIdx.x];
  float s  = v.x + v.y + v.z + v.w;
  float ss = v.x * v.x + v.y * v.y + v.z * v.z + v.w * v.w;
  const int lane = threadIdx.x & 63, wave = threadIdx.x >> 6;
#pragma unroll
  for (int o = 32; o; o >>= 1) { s += __shfl_xor(s, o); ss += __shfl_xor(ss, o); }
  __shared__ float rs[4], rss[4];
  if (lane == 0) { rs[wave] = s; rss[wave] = ss; }
  __syncthreads();
  s  = rs[0] + rs[1] + rs[2] + rs[3];
  ss = rss[0] + rss[1] + rss[2] + rss[3];
  const float mean = s * (1.0f / DIM);
  const float var  = ss * (1.0f / DIM) - mean * mean;
  const float rstd = rsqrtf(var + 1e-5f);
  const float4 g = ((const float4*)gamma)[threadIdx.x];
  const float4 b = ((const float4*)beta)[threadIdx.x];
  union { bf16 h[4]; uint2 u; } pk;
  pk.h[0] = __float2bfloat16(g.x * (v.x - mean) * rstd + b.x);
  pk.h[1] = __float2bfloat16(g.y * (v.y - mean) * rstd + b.y);
  pk.h[2] = __float2bfloat16(g.z * (v.z - mean) * rstd + b.z);
  pk.h[3] = __float2bfloat16(g.w * (v.w - mean) * rstd + b.w);
  ((uint2*)(out + row * DIM))[threadIdx.x] = pk.u;
}

// ---------------------------------------------------------------------------
__global__ __launch_bounds__(256) void softmax_kernel(bf16* __restrict__ scores)
{
  const long row = blockIdx.x;
  bf16* rp = scores + row * (long)SEQ;
  union { bf16 h[8]; uint4 u; } in;
  in.u = ((const uint4*)rp)[threadIdx.x];
  float f[8];
#pragma unroll
  for (int j = 0; j < 8; ++j) f[j] = __bfloat162float(in.h[j]);
  const int lane = threadIdx.x & 63, wave = threadIdx.x >> 6;
  float mx = f[0];
#pragma unroll
  for (int j = 1; j < 8; ++j) mx = fmaxf(mx, f[j]);
#pragma unroll
  for (int o = 32; o; o >>= 1) mx = fmaxf(mx, __shfl_xor(mx, o));
  __shared__ float rm[4], rsum[4];
  if (lane == 0) rm[wave] = mx;
  __syncthreads();
  mx = fmaxf(fmaxf(rm[0], rm[1]), fmaxf(rm[2], rm[3]));
  float sum = 0.0f;
#pragma unroll
  for (int j = 0; j < 8; ++j) { f[j] = expf(f[j] - mx); sum += f[j]; }
#pragma unroll
  for (int o = 32; o; o >>= 1) sum += __shfl_xor(sum, o);
  if (lane == 0) rsum[wave] = sum;
  __syncthreads();
  sum = rsum[0] + rsum[1] + rsum[2] + rsum[3];
  const float inv = 1.0f / sum;
  union { bf16 h[8]; uint4 u; } pk;
#pragma unroll
  for (int j = 0; j < 8; ++j) pk.h[j] = __float2bfloat16(f[j] * inv);
  ((uint4*)rp)[threadIdx.x] = pk.u;
}

// ---------------------------------------------------------------------------
// fused prep (r17, verified): concat(bq,bk) + 4 weight transposes + LN1.
// ---------------------------------------------------------------------------
__global__ __launch_bounds__(256) void prep_kernel(
    const float* __restrict__ Wq, const float* __restrict__ Wk,
    const float* __restrict__ Wv, const float* __restrict__ W1,
    const float* __restrict__ W2,
    const float* __restrict__ bq, const float* __restrict__ bk,
    const float* __restrict__ x, const float* __restrict__ g1,
    const float* __restrict__ be1,
    bf16* __restrict__ WqkT, bf16* __restrict__ WvT,
    bf16* __restrict__ W1T, bf16* __restrict__ W2T,
    float* __restrict__ bqk, bf16* __restrict__ hOut)
{
  int l = blockIdx.x;
  if (l >= 11268) {
    const long row = l - 11268;
    const float4 v = ((const float4*)(x + row * DIM))[threadIdx.x];
    float s  = v.x + v.y + v.z + v.w;
    float ss = v.x * v.x + v.y * v.y + v.z * v.z + v.w * v.w;
    const int lane = threadIdx.x & 63, wave = threadIdx.x >> 6;
#pragma unroll
    for (int o = 32; o; o >>= 1) { s += __shfl_xor(s, o); ss += __shfl_xor(ss, o); }
    __shared__ float rs[4], rss[4];
    if (lane == 0) { rs[wave] = s; rss[wave] = ss; }
    __syncthreads();
    s  = rs[0] + rs[1] + rs[2] + rs[3];
    ss = rss[0] + rss[1] + rss[2] + rss[3];
    const float mean = s * (1.0f / DIM);
    const float var  = ss * (1.0f / DIM) - mean * mean;
    const float rstd = rsqrtf(var + 1e-5f);
    const float4 g = ((const float4*)g1)[threadIdx.x];
    const float4 b = ((const float4*)be1)[threadIdx.x];
    union { bf16 h[4]; uint2 u; } pk;
    pk.h[0] = __float2bfloat16(g.x * (v.x - mean) * rstd + b.x);
    pk.h[1] = __float2bfloat16(g.y * (v.y - mean) * rstd + b.y);
    pk.h[2] = __float2bfloat16(g.z * (v.z - mean) * rstd + b.z);
    pk.h[3] = __float2bfloat16(g.w * (v.w - mean) * rstd + b.w);
    ((uint2*)(hOut + row * DIM))[threadIdx.x] = pk.u;
    return;
  }
  if (l >= 11264) {
    const int i = (l - 11264) * 256 + threadIdx.x;  // i < 1024
    bqk[i] = bq[i]; bqk[DIM + i] = bk[i];
    return;
  }
  __shared__ bf16 tile[32][33];
  const float* in; bf16* out; int ldIn, ldOut, gxw;
  if (l < 2048) {
    const int wsel = l >> 10;
    in = wsel ? Wk : Wq;
    out = WqkT + (long)wsel * DIM * DIM;
    l &= 1023; ldIn = DIM; ldOut = DIM; gxw = 32;
  } else if (l < 3072) {
    in = Wv; out = WvT; l -= 2048; ldIn = DIM; ldOut = DIM; gxw = 32;
  } else if (l < 7168) {
    in = W1; out = W1T; l -= 3072; ldIn = MLPD; ldOut = DIM; gxw = 128;
  } else {
    in = W2; out = W2T; l -= 7168; ldIn = DIM; ldOut = MLPD; gxw = 32;
  }
  const int bxx = l % gxw, byy = l / gxw;
  const int c0 = bxx * 32, r0 = byy * 32;
  const int tx = threadIdx.x & 31, ty = threadIdx.x >> 5;
#pragma unroll
  for (int i = 0; i < 32; i += 8)
    tile[ty + i][tx] = __float2bfloat16(in[(long)(r0 + ty + i) * ldIn + c0 + tx]);
  __syncthreads();
#pragma unroll
  for (int i = 0; i < 32; i += 8)
    out[(long)(c0 + ty + i) * ldOut + r0 + tx] = tile[tx][ty + i];
}

// ---------------------------------------------------------------------------
extern "C" void kernel_launch(void* const* d_in, const int* in_sizes, int n_in,
                              void* d_out, int out_size, void* d_ws, size_t ws_size,
                              hipStream_t stream) {
  const float* x   = (const float*)d_in[0];
  const float* g1  = (const float*)d_in[1];
  const float* be1 = (const float*)d_in[2];
  const float* g2  = (const float*)d_in[3];
  const float* be2 = (const float*)d_in[4];
  const float* Wq  = (const float*)d_in[5];
  const float* bq  = (const float*)d_in[6];
  const float* Wk  = (const float*)d_in[7];
  const float* bk  = (const float*)d_in[8];
  const float* Wv  = (const float*)d_in[9];
  const float* bv  = (const float*)d_in[10];
  const float* W1  = (const float*)d_in[11];
  const float* b1  = (const float*)d_in[12];
  const float* W2  = (const float*)d_in[13];
  const float* b2  = (const float*)d_in[14];
  float* out = (float*)d_out;

  char* ws = (char*)d_ws;
  bf16* WqkT  = (bf16*)(ws + 0);            // 4 MiB  [2048][1024]
  bf16* WvT   = (bf16*)(ws + (4l << 20));   // 2 MiB  [1024][1024]
  bf16* W1T   = (bf16*)(ws + (6l << 20));   // 8 MiB  [4096][1024]
  bf16* W2T   = (bf16*)(ws + (14l << 20));  // 8 MiB  [1024][4096]
  float* bqk  = (float*)(ws + (22l << 20)); // 8 KiB
  bf16* h     = (bf16*)(ws + (23l << 20));  // 16 MiB [8192][1024]
  bf16* qk    = (bf16*)(ws + (39l << 20));  // 32 MiB [8192][2048]
  bf16* vT    = (bf16*)(ws + (71l << 20));  // 16 MiB [4][1024][2048]
  bf16* sc    = (bf16*)(ws + (87l << 20));  // 32 MiB [4][2048][2048] bf16
  bf16* g_act = (bf16*)sc;                  // 64 MiB [8192][4096], seq. reuse

  const int SMEM = 131072;
  hipFuncSetAttribute(reinterpret_cast<const void*>(&gemm256<0>),
                      hipFuncAttributeMaxDynamicSharedMemorySize, SMEM);
  hipFuncSetAttribute(reinterpret_cast<const void*>(&gemm256<5>),
                      hipFuncAttributeMaxDynamicSharedMemorySize, SMEM);

  const dim3 blk(256), gblk(512);

  // fused prep + LN1
  prep_kernel<<<11268 + ROWS, blk, 0, stream>>>(
      Wq, Wk, Wv, W1, W2, bq, bk, x, g1, be1,
      WqkT, WvT, W1T, W2T, bqk, h);

  // QK projections (gemm256, 256 wg)
  gemm256<0><<<dim3(8, 32, 1), gblk, SMEM, stream>>>(
      h, 0, DIM, WqkT, 0, DIM, qk, 0, 2 * DIM, bqk, DIM, 1.0f);

  // V^T direct (gemm128, 512 wg — r17-measured faster than deep)
  gemm128<6><<<dim3(16, 8, NB), blk, 0, stream>>>(
      WvT, 0, DIM, h, (long)SEQ * DIM, DIM,
      vT, (long)DIM * SEQ, SEQ, bv, nullptr, 0, 0, DIM, 1.0f);

  // scores = q @ k^T * (1/32) -> bf16 (gemm256, 256 wg)
  gemm256<5><<<dim3(8, 8, NB), gblk, SMEM, stream>>>(
      qk, (long)SEQ * 2 * DIM, 2 * DIM, qk + DIM, (long)SEQ * 2 * DIM,
      2 * DIM, sc, (long)SEQ * SEQ, SEQ, nullptr, DIM, 0.03125f);

  // softmax rows (bf16 in/out, in-place)
  softmax_kernel<<<ROWS, blk, 0, stream>>>(sc);

  // x1 = P @ V + x -> d_out (gemm128, 512 wg — r17-measured)
  gemm128<2><<<dim3(8, 16, NB), blk, 0, stream>>>(
      sc, (long)SEQ * SEQ, SEQ, vT, (long)DIM * SEQ, SEQ,
      out, (long)SEQ * DIM, DIM, nullptr, x, (long)SEQ * DIM, DIM, SEQ, 1.0f);

  // LN2
  ln_kernel<<<ROWS, blk, 0, stream>>>(out, g2, be2, h);

  // MLP1 (gemm128, 2048 wg — r18 A/B: 4 blocks/CU wins)
  gemm128<3><<<dim3(32, 64, 1), blk, 0, stream>>>(
      h, 0, DIM, W1T, 0, DIM, g_act, 0, MLPD, b1, nullptr, 0, 0, DIM, 1.0f);

  // MLP2 (gemm128d deep, 512 wg, K=4096 — r18-verified −11 us)
  gemm128d<4><<<dim3(8, 64, 1), blk, 0, stream>>>(
      g_act, 0, MLPD, W2T, 0, MLPD, out, 0, DIM, b2, out, 0, DIM, MLPD, 1.0f);
}

// Round 21
// 338.523 us; speedup vs baseline: 1.0070x; 1.0070x over previous
//
#include <hip/hip_runtime.h>
#include <hip/hip_bf16.h>
#include <math.h>

typedef __bf16 bf16x8 __attribute__((ext_vector_type(8)));
typedef float  f32x4  __attribute__((ext_vector_type(4)));
typedef __hip_bfloat16 bf16;

#define DIM  1024
#define MLPD 4096
#define NB   4
#define SEQ  2048
#define ROWS (NB * SEQ) /* 8192 */

__device__ __forceinline__ void gload_lds16(const void* g, void* l) {
  __builtin_amdgcn_global_load_lds(
      (__attribute__((address_space(1))) void*)(g),
      (__attribute__((address_space(3))) void*)(l), 16, 0, 0);
}

__device__ __forceinline__ void bar() {
  asm volatile("" ::: "memory");
  __builtin_amdgcn_s_barrier();
  asm volatile("" ::: "memory");
}

template <int N>
__device__ __forceinline__ void vmw() {
  asm volatile("s_waitcnt vmcnt(%0)" ::"n"(N) : "memory");
}

// exact-GELU via A&S 7.1.26 erf approx (max err ~1.5e-7 << 0.09 headroom).
__device__ __forceinline__ float gelu_exact_fast(float v) {
  const float x  = v * 0.70710678118654752f;
  const float ax = fabsf(x);
  const float t  = __builtin_amdgcn_rcpf(1.0f + 0.3275911f * ax);
  const float p  = t * (0.254829592f +
                   t * (-0.284496736f +
                   t * (1.421413741f +
                   t * (-1.453152027f + t * 1.061405429f))));
  float erf = 1.0f - p * __expf(-x * x);
  erf = copysignf(erf, x);
  return 0.5f * v * (1.0f + erf);
}

// ---------------------------------------------------------------------------
// 256x256 8-phase GEMM (r13-r19, verified): QK-proj + scores.
// EPI: 0=+bias->bf16 | 5=*scale->bf16
// ---------------------------------------------------------------------------
template <int EPI>
__global__ __launch_bounds__(512, 2) void gemm256(
    const bf16* __restrict__ A,  long aBatch, int lda,
    const bf16* __restrict__ Bt, long bBatch, int ldb,
    void* __restrict__ Cout,     long cBatch, int ldc,
    const float* __restrict__ bias, int K, float scale)
{
  extern __shared__ char smem[];

  const int gx = gridDim.x, gy = gridDim.y;
  int flat = blockIdx.x + gx * (blockIdx.y + gy * blockIdx.z);
  const int nwg = gx * gy * gridDim.z;
  flat = (flat & 7) * (nwg >> 3) + (flat >> 3);
  const int bx = flat % gx;
  const int t2 = flat / gx;
  const int by = t2 % gy;
  const int bz = t2 / gy;

  const long rowBase = (long)by * 256;
  const long colBase = (long)bx * 256;
  const long ldaB = (long)lda * 2, ldbB = (long)ldb * 2;
  const char* Ag = (const char*)(A + bz * aBatch + rowBase * lda);
  const char* Bg = (const char*)(Bt + bz * bBatch + colBase * ldb);

  const int tid  = threadIdx.x;
  const int lane = tid & 63;
  const int wave = tid >> 6;
  const int wm = wave >> 2, wn = wave & 3;
  const int fr = lane & 15, fq = lane >> 4;
  const int fh2 = fr >> 1;
  const int sA = (((fr & 1) << 2) | fq) ^ fh2;
  const int rdCom = fh2 * 128 + sA * 16;

  long offA[2], offB[2];
#pragma unroll
  for (int li = 0; li < 2; ++li) {
    const int d = li * 512 + tid;
    {
      const int wms = d >> 9, kks = (d >> 8) & 1, w = d & 255;
      const int pr = w >> 3, s = w & 7, u = s ^ (pr & 7);
      offA[li] = (long)(wms * 128 + pr * 2 + (u >> 2)) * ldaB +
                 kks * 64 + (u & 3) * 16;
    }
    {
      const int wns = d >> 8, kkb = (d >> 7) & 1, w = d & 127;
      const int pr = w >> 3, s = w & 7, u = s ^ (pr & 7);
      offB[li] = (long)(wns * 64 + pr * 2 + (u >> 2)) * ldbB +
                 kkb * 64 + (u & 3) * 16;
    }
  }
  const int dstOff = tid * 16;
  const long aHalf = ldaB << 6;
  const long bHalf = ldbB << 5;

  const int NT = K >> 6;

  bf16x8 a[4][2], b[2][2][2];
  f32x4 acc[8][4] = {};

#define STG_A(J, mh)                                                           \
  do {                                                                         \
    char* _d = smem + (((J) & 1) << 16) + (mh) * 16384 + dstOff;               \
    const char* _s = Ag + (J) * 128 + (mh) * aHalf;                            \
    gload_lds16(_s + offA[0], _d);                                             \
    gload_lds16(_s + offA[1], _d + 8192);                                      \
  } while (0)

#define STG_B(J, nh)                                                           \
  do {                                                                         \
    char* _d = smem + (((J) & 1) << 16) + 32768 + (nh) * 16384 + dstOff;       \
    const char* _s = Bg + (J) * 128 + (nh) * bHalf;                            \
    gload_lds16(_s + offB[0], _d);                                             \
    gload_lds16(_s + offB[1], _d + 8192);                                      \
  } while (0)

#define LDA(mh, J)                                                             \
  do {                                                                         \
    const char* _b = smem + (((J) & 1) << 16) + (mh) * 16384 + wm * 8192 +     \
                     rdCom;                                                    \
    _Pragma("unroll") for (int m = 0; m < 4; ++m)                              \
      _Pragma("unroll") for (int kk = 0; kk < 2; ++kk)                         \
        a[m][kk] = *(const bf16x8*)(_b + kk * 4096 + m * 1024);                \
  } while (0)

#define LDB(nh, J)                                                             \
  do {                                                                         \
    const char* _b = smem + (((J) & 1) << 16) + 32768 + (nh) * 16384 +         \
                     wn * 4096 + rdCom;                                        \
    _Pragma("unroll") for (int n = 0; n < 2; ++n)                              \
      _Pragma("unroll") for (int kk = 0; kk < 2; ++kk)                         \
        b[nh][n][kk] = *(const bf16x8*)(_b + kk * 2048 + n * 1024);            \
  } while (0)

#define MM(mh, nh)                                                             \
  do {                                                                         \
    __builtin_amdgcn_s_setprio(1);                                             \
    _Pragma("unroll") for (int m = 0; m < 4; ++m)                              \
      _Pragma("unroll") for (int n = 0; n < 2; ++n)                            \
        _Pragma("unroll") for (int kk = 0; kk < 2; ++kk)                       \
          acc[(mh) * 4 + m][(nh) * 2 + n] =                                    \
              __builtin_amdgcn_mfma_f32_16x16x32_bf16(                         \
                  a[m][kk], b[nh][n][kk], acc[(mh) * 4 + m][(nh) * 2 + n],     \
                  0, 0, 0);                                                    \
    __builtin_amdgcn_s_setprio(0);                                             \
  } while (0)

#define LGKM0 asm volatile("s_waitcnt lgkmcnt(0)" ::: "memory")

#define TILE(J, S1, S2, VN)                                                    \
  do {                                                                         \
    LDA(0, J); LDB(0, J);                                                      \
    if (S1) STG_A((J) + 1, 1);                                                 \
    bar(); LGKM0; MM(0, 0); bar();                                             \
    LDB(1, J);                                                                 \
    if (S2) STG_A((J) + 2, 0);                                                 \
    bar(); LGKM0; MM(0, 1); bar();                                             \
    LDA(1, J);                                                                 \
    if (S2) STG_B((J) + 2, 0);                                                 \
    bar(); LGKM0; MM(1, 1); bar();                                             \
    if (S2) STG_B((J) + 2, 1);                                                 \
    vmw<VN>(); bar(); MM(1, 0); bar();                                         \
  } while (0)

  STG_A(0, 0); STG_B(0, 0); STG_B(0, 1); STG_A(0, 1);
  STG_A(1, 0); STG_B(1, 0); STG_B(1, 1);
  vmw<6>(); bar();

  for (int j = 0; j < NT - 2; ++j) TILE(j, true, true, 6);
  TILE(NT - 2, true, false, 0);
  TILE(NT - 1, false, false, 63);

#undef STG_A
#undef STG_B
#undef LDA
#undef LDB
#undef MM
#undef TILE

#pragma unroll
  for (int mh = 0; mh < 2; ++mh)
#pragma unroll
    for (int m = 0; m < 4; ++m)
#pragma unroll
      for (int nh = 0; nh < 2; ++nh)
#pragma unroll
        for (int n = 0; n < 2; ++n) {
          const long col = colBase + wn * 64 + nh * 32 + n * 16 + fr;
#pragma unroll
          for (int e = 0; e < 4; ++e) {
            const long r = rowBase + wm * 128 + mh * 64 + m * 16 + fq * 4 + e;
            float v = acc[mh * 4 + m][nh * 2 + n][e];
            if constexpr (EPI == 0) {
              v += bias[col];
              ((bf16*)Cout)[bz * cBatch + r * ldc + col] = __float2bfloat16(v);
            } else {  // 5
              ((bf16*)Cout)[bz * cBatch + r * ldc + col] =
                  __float2bfloat16(v * scale);
            }
          }
        }
}

// ---------------------------------------------------------------------------
// r10 128x128 GEMM (MLP1 — 2048 wg where 4 blocks/CU wins): BK=32, 4 waves,
// 32 KiB dbuf, period-2 drains, conflict-free row-pair LDS.
// EPI: 3=+bias,gelu->bf16
// ---------------------------------------------------------------------------
template <int EPI>
__global__ __launch_bounds__(256, 4) void gemm128(
    const bf16* __restrict__ A,  long aBatch, int lda,
    const bf16* __restrict__ Bt, long bBatch, int ldb,
    void* __restrict__ Cout,     long cBatch, int ldc,
    const float* __restrict__ bias,
    const float* __restrict__ resid, long rBatch, int ldr,
    int K, float scale)
{
  __shared__ char smem[2][16384];

  const int gx = gridDim.x, gy = gridDim.y;
  const int n = gx * gy * gridDim.z;
  const int f = blockIdx.x + gx * (blockIdx.y + gy * blockIdx.z);
  const int o = (f & 7) * (n >> 3) + (f >> 3);
  const int sx = gx >> 3;
  int st = o >> 6;
  const int w = o & 63;
  const int spz = sx * (gy >> 3);
  const int bz = st / spz; st -= bz * spz;
  const int sty = st / sx, stx = st - sty * sx;
  const int by = sty * 8 + (w >> 3), bx = stx * 8 + (w & 7);

  const long rowBase = (long)by * 128;
  const long colBase = (long)bx * 128;
  const long ldaB = (long)lda * 2, ldbB = (long)ldb * 2;
  const char* Ag = (const char*)(A + bz * aBatch + rowBase * lda);
  const char* Bg = (const char*)(Bt + bz * bBatch + colBase * ldb);

  const int tid  = threadIdx.x;
  const int lane = tid & 63;
  const int wave = tid >> 6;
  const int wm = wave >> 1, wn = wave & 1;
  const int fr = lane & 15, fq = lane >> 4;

  const int fh = fr >> 1;
  const int sA = (((fr & 1) << 2) | fq) ^ fh;
  const int laneRd = fh * 128 + sA * 16;
  const int abase = wm * 4096 + laneRd;
  const int bbase = 8192 + wn * 4096 + laneRd;

  const int t0   = wave * 128 + lane;
  const int r2   = t0 >> 3;
  const int u0   = (t0 & 7) ^ (r2 & 7);
  const int row0 = r2 * 2 + (u0 >> 2);
  const int kc0  = u0 & 3;
  const char* aSrc0 = Ag + (long)row0 * ldaB + kc0 * 16;
  const char* aSrc1 = aSrc0 + 16 * ldaB;
  const char* bSrc0 = Bg + (long)row0 * ldbB + kc0 * 16;
  const char* bSrc1 = bSrc0 + 16 * ldbB;
  const int doff = wave * 2048 + lane * 16;

  const int NT = K >> 5;
  f32x4 acc[4][4] = {};

#define STAGE(WB)                                                              \
  do {                                                                         \
    gload_lds16(aSrc0, &smem[WB][doff]);                                       \
    gload_lds16(aSrc1, &smem[WB][doff + 1024]);                                \
    gload_lds16(bSrc0, &smem[WB][8192 + doff]);                                \
    gload_lds16(bSrc1, &smem[WB][8192 + doff + 1024]);                         \
    aSrc0 += 64; aSrc1 += 64; bSrc0 += 64; bSrc1 += 64;                        \
  } while (0)

#define READMM(RB)                                                             \
  do {                                                                         \
    const char* _r = &smem[RB][0];                                             \
    bf16x8 av[4], bv_[4];                                                      \
    _Pragma("unroll") for (int m = 0; m < 4; ++m)                              \
      av[m] = *(const bf16x8*)(_r + abase + m * 1024);                         \
    _Pragma("unroll") for (int nn = 0; nn < 4; ++nn)                           \
      bv_[nn] = *(const bf16x8*)(_r + bbase + nn * 1024);                      \
    __builtin_amdgcn_s_setprio(1);                                             \
    _Pragma("unroll") for (int m = 0; m < 4; ++m)                              \
      _Pragma("unroll") for (int nn = 0; nn < 4; ++nn)                         \
        acc[m][nn] = __builtin_amdgcn_mfma_f32_16x16x32_bf16(                  \
            av[m], bv_[nn], acc[m][nn], 0, 0, 0);                              \
    __builtin_amdgcn_s_setprio(0);                                             \
  } while (0)

  for (int t = 0; t < NT; t += 2) {
    STAGE(0);
    STAGE(1);
    vmw<0>(); bar();
    READMM(0);
    READMM(1);
    bar();
  }

#undef STAGE
#undef READMM

#pragma unroll
  for (int m = 0; m < 4; ++m) {
#pragma unroll
    for (int nn = 0; nn < 4; ++nn) {
      const long col = colBase + wn * 64 + nn * 16 + fr;
#pragma unroll
      for (int e = 0; e < 4; ++e) {
        const long r = rowBase + wm * 64 + m * 16 + fq * 4 + e;
        float v = acc[m][nn][e];
        if constexpr (EPI == 3) {
          v += bias[col];
          ((bf16*)Cout)[bz * cBatch + r * ldc + col] =
              __float2bfloat16(gelu_exact_fast(v));
        }
      }
    }
  }
}

// ---------------------------------------------------------------------------
// r18 DEEP 128x128 GEMM (512-wg GEMMs: vT, PV, MLP2 — r19-measured best).
// 4 sub-buffers (2 pairs, 64 KiB); period-old vmcnt(8); requires K%128==0.
// EPI: 2=+resid->fp32 | 4=+bias+resid->fp32 | 6=+bias[ROW]->bf16
// ---------------------------------------------------------------------------
template <int EPI>
__global__ __launch_bounds__(256, 2) void gemm128d(
    const bf16* __restrict__ A,  long aBatch, int lda,
    const bf16* __restrict__ Bt, long bBatch, int ldb,
    void* __restrict__ Cout,     long cBatch, int ldc,
    const float* __restrict__ bias,
    const float* __restrict__ resid, long rBatch, int ldr,
    int K, float scale)
{
  __shared__ char smem[4][16384];

  const int gx = gridDim.x, gy = gridDim.y;
  const int n = gx * gy * gridDim.z;
  const int f = blockIdx.x + gx * (blockIdx.y + gy * blockIdx.z);
  const int o = (f & 7) * (n >> 3) + (f >> 3);
  const int sx = gx >> 3;
  int st = o >> 6;
  const int w = o & 63;
  const int spz = sx * (gy >> 3);
  const int bz = st / spz; st -= bz * spz;
  const int sty = st / sx, stx = st - sty * sx;
  const int by = sty * 8 + (w >> 3), bx = stx * 8 + (w & 7);

  const long rowBase = (long)by * 128;
  const long colBase = (long)bx * 128;
  const long ldaB = (long)lda * 2, ldbB = (long)ldb * 2;
  const char* Ag = (const char*)(A + bz * aBatch + rowBase * lda);
  const char* Bg = (const char*)(Bt + bz * bBatch + colBase * ldb);

  const int tid  = threadIdx.x;
  const int lane = tid & 63;
  const int wave = tid >> 6;
  const int wm = wave >> 1, wn = wave & 1;
  const int fr = lane & 15, fq = lane >> 4;

  const int fh = fr >> 1;
  const int sA = (((fr & 1) << 2) | fq) ^ fh;
  const int laneRd = fh * 128 + sA * 16;
  const int abase = wm * 4096 + laneRd;
  const int bbase = 8192 + wn * 4096 + laneRd;

  const int t0   = wave * 128 + lane;
  const int r2   = t0 >> 3;
  const int u0   = (t0 & 7) ^ (r2 & 7);
  const int row0 = r2 * 2 + (u0 >> 2);
  const int kc0  = u0 & 3;
  const char* aSrc0 = Ag + (long)row0 * ldaB + kc0 * 16;
  const char* aSrc1 = aSrc0 + 16 * ldaB;
  const char* bSrc0 = Bg + (long)row0 * ldbB + kc0 * 16;
  const char* bSrc1 = bSrc0 + 16 * ldbB;
  const int doff = wave * 2048 + lane * 16;

  const int NP = K >> 6;   // periods of 2 K-tiles; NP even required
  f32x4 acc[4][4] = {};

#define STAGE(WB)                                                              \
  do {                                                                         \
    gload_lds16(aSrc0, &smem[WB][doff]);                                       \
    gload_lds16(aSrc1, &smem[WB][doff + 1024]);                                \
    gload_lds16(bSrc0, &smem[WB][8192 + doff]);                                \
    gload_lds16(bSrc1, &smem[WB][8192 + doff + 1024]);                         \
    aSrc0 += 64; aSrc1 += 64; bSrc0 += 64; bSrc1 += 64;                        \
  } while (0)

#define READMM(RB)                                                             \
  do {                                                                         \
    const char* _r = &smem[RB][0];                                             \
    bf16x8 av[4], bv_[4];                                                      \
    _Pragma("unroll") for (int m = 0; m < 4; ++m)                              \
      av[m] = *(const bf16x8*)(_r + abase + m * 1024);                         \
    _Pragma("unroll") for (int nn = 0; nn < 4; ++nn)                           \
      bv_[nn] = *(const bf16x8*)(_r + bbase + nn * 1024);                      \
    __builtin_amdgcn_s_setprio(1);                                             \
    _Pragma("unroll") for (int m = 0; m < 4; ++m)                              \
      _Pragma("unroll") for (int nn = 0; nn < 4; ++nn)                         \
        acc[m][nn] = __builtin_amdgcn_mfma_f32_16x16x32_bf16(                  \
            av[m], bv_[nn], acc[m][nn], 0, 0, 0);                              \
    __builtin_amdgcn_s_setprio(0);                                             \
  } while (0)

  // prologue: period-0 pair (tiles 0,1) -> subs 0,1
  STAGE(0); STAGE(1);

  for (int it = 0; it < NP; it += 2) {
    STAGE(2); STAGE(3);
    vmw<8>(); bar();            // retires pair{0,1}'s loads (1 period old)
    READMM(0); READMM(1);
    bar();
    if (it + 2 < NP) { STAGE(0); STAGE(1); vmw<8>(); }
    else vmw<0>();
    bar();
    READMM(2); READMM(3);
    bar();
  }

#undef STAGE
#undef READMM

#pragma unroll
  for (int m = 0; m < 4; ++m) {
#pragma unroll
    for (int nn = 0; nn < 4; ++nn) {
      const long col = colBase + wn * 64 + nn * 16 + fr;
#pragma unroll
      for (int e = 0; e < 4; ++e) {
        const long r = rowBase + wm * 64 + m * 16 + fq * 4 + e;
        float v = acc[m][nn][e];
        if constexpr (EPI == 2) {
          v += resid[bz * rBatch + r * ldr + col];
          ((float*)Cout)[bz * cBatch + r * ldc + col] = v;
        } else if constexpr (EPI == 4) {
          v += bias[col] + resid[r * (long)ldr + col];
          ((float*)Cout)[bz * cBatch + r * ldc + col] = v;
        } else {  // 6: +bias indexed by ROW, bf16 out
          v += bias[r];
          ((bf16*)Cout)[bz * cBatch + r * ldc + col] = __float2bfloat16(v);
        }
      }
    }
  }
}

// ---------------------------------------------------------------------------
__global__ __launch_bounds__(256) void ln_kernel(
    const float* __restrict__ x, const float* __restrict__ gamma,
    const float* __restrict__ beta, bf16* __restrict__ out)
{
  const long row = blockIdx.x;
  const float4 v = ((const float4*)(x + row * DIM))[threadIdx.x];
  float s  = v.x + v.y + v.z + v.w;
  float ss = v.x * v.x + v.y * v.y + v.z * v.z + v.w * v.w;
  const int lane = threadIdx.x & 63, wave = threadIdx.x >> 6;
#pragma unroll
  for (int o = 32; o; o >>= 1) { s += __shfl_xor(s, o); ss += __shfl_xor(ss, o); }
  __shared__ float rs[4], rss[4];
  if (lane == 0) { rs[wave] = s; rss[wave] = ss; }
  __syncthreads();
  s  = rs[0] + rs[1] + rs[2] + rs[3];
  ss = rss[0] + rss[1] + rss[2] + rss[3];
  const float mean = s * (1.0f / DIM);
  const float var  = ss * (1.0f / DIM) - mean * mean;
  const float rstd = rsqrtf(var + 1e-5f);
  const float4 g = ((const float4*)gamma)[threadIdx.x];
  const float4 b = ((const float4*)beta)[threadIdx.x];
  union { bf16 h[4]; uint2 u; } pk;
  pk.h[0] = __float2bfloat16(g.x * (v.x - mean) * rstd + b.x);
  pk.h[1] = __float2bfloat16(g.y * (v.y - mean) * rstd + b.y);
  pk.h[2] = __float2bfloat16(g.z * (v.z - mean) * rstd + b.z);
  pk.h[3] = __float2bfloat16(g.w * (v.w - mean) * rstd + b.w);
  ((uint2*)(out + row * DIM))[threadIdx.x] = pk.u;
}

// ---------------------------------------------------------------------------
__global__ __launch_bounds__(256) void softmax_kernel(bf16* __restrict__ scores)
{
  const long row = blockIdx.x;
  bf16* rp = scores + row * (long)SEQ;
  union { bf16 h[8]; uint4 u; } in;
  in.u = ((const uint4*)rp)[threadIdx.x];
  float f[8];
#pragma unroll
  for (int j = 0; j < 8; ++j) f[j] = __bfloat162float(in.h[j]);
  const int lane = threadIdx.x & 63, wave = threadIdx.x >> 6;
  float mx = f[0];
#pragma unroll
  for (int j = 1; j < 8; ++j) mx = fmaxf(mx, f[j]);
#pragma unroll
  for (int o = 32; o; o >>= 1) mx = fmaxf(mx, __shfl_xor(mx, o));
  __shared__ float rm[4], rsum[4];
  if (lane == 0) rm[wave] = mx;
  __syncthreads();
  mx = fmaxf(fmaxf(rm[0], rm[1]), fmaxf(rm[2], rm[3]));
  float sum = 0.0f;
#pragma unroll
  for (int j = 0; j < 8; ++j) { f[j] = expf(f[j] - mx); sum += f[j]; }
#pragma unroll
  for (int o = 32; o; o >>= 1) sum += __shfl_xor(sum, o);
  if (lane == 0) rsum[wave] = sum;
  __syncthreads();
  sum = rsum[0] + rsum[1] + rsum[2] + rsum[3];
  const float inv = 1.0f / sum;
  union { bf16 h[8]; uint4 u; } pk;
#pragma unroll
  for (int j = 0; j < 8; ++j) pk.h[j] = __float2bfloat16(f[j] * inv);
  ((uint4*)rp)[threadIdx.x] = pk.u;
}

// ---------------------------------------------------------------------------
// fused prep (r17, verified): concat(bq,bk) + 4 weight transposes + LN1.
// ---------------------------------------------------------------------------
__global__ __launch_bounds__(256) void prep_kernel(
    const float* __restrict__ Wq, const float* __restrict__ Wk,
    const float* __restrict__ Wv, const float* __restrict__ W1,
    const float* __restrict__ W2,
    const float* __restrict__ bq, const float* __restrict__ bk,
    const float* __restrict__ x, const float* __restrict__ g1,
    const float* __restrict__ be1,
    bf16* __restrict__ WqkT, bf16* __restrict__ WvT,
    bf16* __restrict__ W1T, bf16* __restrict__ W2T,
    float* __restrict__ bqk, bf16* __restrict__ hOut)
{
  int l = blockIdx.x;
  if (l >= 11268) {
    const long row = l - 11268;
    const float4 v = ((const float4*)(x + row * DIM))[threadIdx.x];
    float s  = v.x + v.y + v.z + v.w;
    float ss = v.x * v.x + v.y * v.y + v.z * v.z + v.w * v.w;
    const int lane = threadIdx.x & 63, wave = threadIdx.x >> 6;
#pragma unroll
    for (int o = 32; o; o >>= 1) { s += __shfl_xor(s, o); ss += __shfl_xor(ss, o); }
    __shared__ float rs[4], rss[4];
    if (lane == 0) { rs[wave] = s; rss[wave] = ss; }
    __syncthreads();
    s  = rs[0] + rs[1] + rs[2] + rs[3];
    ss = rss[0] + rss[1] + rss[2] + rss[3];
    const float mean = s * (1.0f / DIM);
    const float var  = ss * (1.0f / DIM) - mean * mean;
    const float rstd = rsqrtf(var + 1e-5f);
    const float4 g = ((const float4*)g1)[threadIdx.x];
    const float4 b = ((const float4*)be1)[threadIdx.x];
    union { bf16 h[4]; uint2 u; } pk;
    pk.h[0] = __float2bfloat16(g.x * (v.x - mean) * rstd + b.x);
    pk.h[1] = __float2bfloat16(g.y * (v.y - mean) * rstd + b.y);
    pk.h[2] = __float2bfloat16(g.z * (v.z - mean) * rstd + b.z);
    pk.h[3] = __float2bfloat16(g.w * (v.w - mean) * rstd + b.w);
    ((uint2*)(hOut + row * DIM))[threadIdx.x] = pk.u;
    return;
  }
  if (l >= 11264) {
    const int i = (l - 11264) * 256 + threadIdx.x;  // i < 1024
    bqk[i] = bq[i]; bqk[DIM + i] = bk[i];
    return;
  }
  __shared__ bf16 tile[32][33];
  const float* in; bf16* out; int ldIn, ldOut, gxw;
  if (l < 2048) {
    const int wsel = l >> 10;
    in = wsel ? Wk : Wq;
    out = WqkT + (long)wsel * DIM * DIM;
    l &= 1023; ldIn = DIM; ldOut = DIM; gxw = 32;
  } else if (l < 3072) {
    in = Wv; out = WvT; l -= 2048; ldIn = DIM; ldOut = DIM; gxw = 32;
  } else if (l < 7168) {
    in = W1; out = W1T; l -= 3072; ldIn = MLPD; ldOut = DIM; gxw = 128;
  } else {
    in = W2; out = W2T; l -= 7168; ldIn = DIM; ldOut = MLPD; gxw = 32;
  }
  const int bxx = l % gxw, byy = l / gxw;
  const int c0 = bxx * 32, r0 = byy * 32;
  const int tx = threadIdx.x & 31, ty = threadIdx.x >> 5;
#pragma unroll
  for (int i = 0; i < 32; i += 8)
    tile[ty + i][tx] = __float2bfloat16(in[(long)(r0 + ty + i) * ldIn + c0 + tx]);
  __syncthreads();
#pragma unroll
  for (int i = 0; i < 32; i += 8)
    out[(long)(c0 + ty + i) * ldOut + r0 + tx] = tile[tx][ty + i];
}

// ---------------------------------------------------------------------------
extern "C" void kernel_launch(void* const* d_in, const int* in_sizes, int n_in,
                              void* d_out, int out_size, void* d_ws, size_t ws_size,
                              hipStream_t stream) {
  const float* x   = (const float*)d_in[0];
  const float* g1  = (const float*)d_in[1];
  const float* be1 = (const float*)d_in[2];
  const float* g2  = (const float*)d_in[3];
  const float* be2 = (const float*)d_in[4];
  const float* Wq  = (const float*)d_in[5];
  const float* bq  = (const float*)d_in[6];
  const float* Wk  = (const float*)d_in[7];
  const float* bk  = (const float*)d_in[8];
  const float* Wv  = (const float*)d_in[9];
  const float* bv  = (const float*)d_in[10];
  const float* W1  = (const float*)d_in[11];
  const float* b1  = (const float*)d_in[12];
  const float* W2  = (const float*)d_in[13];
  const float* b2  = (const float*)d_in[14];
  float* out = (float*)d_out;

  char* ws = (char*)d_ws;
  bf16* WqkT  = (bf16*)(ws + 0);            // 4 MiB  [2048][1024]
  bf16* WvT   = (bf16*)(ws + (4l << 20));   // 2 MiB  [1024][1024]
  bf16* W1T   = (bf16*)(ws + (6l << 20));   // 8 MiB  [4096][1024]
  bf16* W2T   = (bf16*)(ws + (14l << 20));  // 8 MiB  [1024][4096]
  float* bqk  = (float*)(ws + (22l << 20)); // 8 KiB
  bf16* h     = (bf16*)(ws + (23l << 20));  // 16 MiB [8192][1024]
  bf16* qk    = (bf16*)(ws + (39l << 20));  // 32 MiB [8192][2048]
  bf16* vT    = (bf16*)(ws + (71l << 20));  // 16 MiB [4][1024][2048]
  bf16* sc    = (bf16*)(ws + (87l << 20));  // 32 MiB [4][2048][2048] bf16
  bf16* g_act = (bf16*)sc;                  // 64 MiB [8192][4096], seq. reuse

  const int SMEM = 131072;
  hipFuncSetAttribute(reinterpret_cast<const void*>(&gemm256<0>),
                      hipFuncAttributeMaxDynamicSharedMemorySize, SMEM);
  hipFuncSetAttribute(reinterpret_cast<const void*>(&gemm256<5>),
                      hipFuncAttributeMaxDynamicSharedMemorySize, SMEM);

  const dim3 blk(256), gblk(512);

  // fused prep + LN1
  prep_kernel<<<11268 + ROWS, blk, 0, stream>>>(
      Wq, Wk, Wv, W1, W2, bq, bk, x, g1, be1,
      WqkT, WvT, W1T, W2T, bqk, h);

  // QK projections (gemm256, 256 wg)
  gemm256<0><<<dim3(8, 32, 1), gblk, SMEM, stream>>>(
      h, 0, DIM, WqkT, 0, DIM, qk, 0, 2 * DIM, bqk, DIM, 1.0f);

  // V^T direct (gemm128d deep, 512 wg, K=1024 — r19-measured best)
  gemm128d<6><<<dim3(16, 8, NB), blk, 0, stream>>>(
      WvT, 0, DIM, h, (long)SEQ * DIM, DIM,
      vT, (long)DIM * SEQ, SEQ, bv, nullptr, 0, 0, DIM, 1.0f);

  // scores = q @ k^T * (1/32) -> bf16 (gemm256, 256 wg)
  gemm256<5><<<dim3(8, 8, NB), gblk, SMEM, stream>>>(
      qk, (long)SEQ * 2 * DIM, 2 * DIM, qk + DIM, (long)SEQ * 2 * DIM,
      2 * DIM, sc, (long)SEQ * SEQ, SEQ, nullptr, DIM, 0.03125f);

  // softmax rows (bf16 in/out, in-place)
  softmax_kernel<<<ROWS, blk, 0, stream>>>(sc);

  // x1 = P @ V + x -> d_out (gemm128d deep, 512 wg, K=2048 — r19)
  gemm128d<2><<<dim3(8, 16, NB), blk, 0, stream>>>(
      sc, (long)SEQ * SEQ, SEQ, vT, (long)DIM * SEQ, SEQ,
      out, (long)SEQ * DIM, DIM, nullptr, x, (long)SEQ * DIM, DIM, SEQ, 1.0f);

  // LN2
  ln_kernel<<<ROWS, blk, 0, stream>>>(out, g2, be2, h);

  // MLP1 (gemm128, 2048 wg — r18 A/B: 4 blocks/CU wins)
  gemm128<3><<<dim3(32, 64, 1), blk, 0, stream>>>(
      h, 0, DIM, W1T, 0, DIM, g_act, 0, MLPD, b1, nullptr, 0, 0, DIM, 1.0f);

  // MLP2 (gemm128d deep, 512 wg, K=4096 — r18-verified −11 us)
  gemm128d<4><<<dim3(8, 64, 1), blk, 0, stream>>>(
      g_act, 0, MLPD, W2T, 0, MLPD, out, 0, DIM, b2, out, 0, DIM, MLPD, 1.0f);
}